// Round 1
// baseline (157.830 us; speedup 1.0000x reference)
//
#include <hip/hip_runtime.h>
#include <math.h>

#define N_ROWS 16384
#define D_INP  1024
#define D_LAT  128
#define KC     256
#define ALPHA_F 1.0f
#define EPS_F   1e-8f

// ---------------------------------------------------------------------------
// Kernel 1: reconstruction MSE partial sums.  sum((x - a)^2) per block.
// ---------------------------------------------------------------------------
__global__ __launch_bounds__(256) void recon_kernel(const float* __restrict__ x,
                                                    const float* __restrict__ a,
                                                    float* __restrict__ partials) {
    const int tid = threadIdx.x;
    const int gid = blockIdx.x * 256 + tid;
    const int stride = gridDim.x * 256;
    const int n4 = (N_ROWS * D_INP) / 4;  // 4,194,304 float4s
    const float4* x4 = (const float4*)x;
    const float4* a4 = (const float4*)a;
    float acc = 0.f;
    for (int i = gid; i < n4; i += stride) {
        float4 xv = x4[i];
        float4 av = a4[i];
        float d0 = xv.x - av.x;
        float d1 = xv.y - av.y;
        float d2 = xv.z - av.z;
        float d3 = xv.w - av.w;
        acc = fmaf(d0, d0, acc);
        acc = fmaf(d1, d1, acc);
        acc = fmaf(d2, d2, acc);
        acc = fmaf(d3, d3, acc);
    }
    // wave reduce (64 lanes)
    for (int off = 32; off > 0; off >>= 1) acc += __shfl_down(acc, off);
    __shared__ float sw[4];
    const int lane = tid & 63, wv = tid >> 6;
    if (lane == 0) sw[wv] = acc;
    __syncthreads();
    if (tid == 0) partials[blockIdx.x] = sw[0] + sw[1] + sw[2] + sw[3];
}

// ---------------------------------------------------------------------------
// Kernel 2: clustering loss partial sums.  32 rows per block, 256 threads.
//   phase 1: t[n,k] = h_n . R_k ; e = exp(-sqrt(max(h2 + r2 - 2t, 0)))
//   phase 2: wc_d = (sum_k e_k R_kd) / (sum_k e_k + EPS); sum_d (h_d - wc_d)^2
// ---------------------------------------------------------------------------
__global__ __launch_bounds__(256) void cluster_kernel(const float* __restrict__ h,
                                                      const float* __restrict__ R,
                                                      float* __restrict__ partials) {
    constexpr int ROWS = 32;
    const int tid = threadIdx.x;
    const int rbase = blockIdx.x * ROWS;

    __shared__ float sh_h[ROWS * 132];   // row stride 132 floats (33 float4) -> bank spread
    __shared__ float sh_e[ROWS * 257];   // row stride 257 -> conflict-free phase-2 reads
    __shared__ float sh_r2[KC];
    __shared__ float sh_h2[ROWS];
    __shared__ float sh_s[ROWS];         // 1 / (sum_e + EPS)
    __shared__ float sh_sp[8 * ROWS];    // per-(kgroup,row) partial sums of e
    __shared__ float sw[4];

    // ---- stage h rows into LDS (coalesced float4) ----
    {
        const float4* hg = (const float4*)(h + (size_t)rbase * D_LAT);
        float4* sh4 = (float4*)sh_h;
        for (int i = tid; i < ROWS * 32; i += 256) {
            int row = i >> 5, c4 = i & 31;
            sh4[row * 33 + c4] = hg[row * 32 + c4];
        }
    }
    // ---- r2 per center (one thread per center) ----
    {
        const float4* Rg = (const float4*)R;
        float s0 = 0.f;
#pragma unroll 8
        for (int c4 = 0; c4 < 32; ++c4) {
            float4 rv = Rg[tid * 32 + c4];
            s0 = fmaf(rv.x, rv.x, s0);
            s0 = fmaf(rv.y, rv.y, s0);
            s0 = fmaf(rv.z, rv.z, s0);
            s0 = fmaf(rv.w, rv.w, s0);
        }
        sh_r2[tid] = s0;
    }
    __syncthreads();
    // ---- h2 per row ----
    if (tid < ROWS) {
        float s0 = 0.f;
#pragma unroll 8
        for (int d = 0; d < D_LAT; ++d) {
            float v = sh_h[tid * 132 + d];
            s0 = fmaf(v, v, s0);
        }
        sh_h2[tid] = s0;
    }
    __syncthreads();

    // ---- phase 1: dots + e, 4-k register blocking ----
    {
        const int row = tid & 31, kg = tid >> 5;  // 8 kgroups x 32 k each
        const float h2 = sh_h2[row];
        const float4* sh4 = (const float4*)sh_h;
        const float4* Rg = (const float4*)R;
        float Spart = 0.f;
        for (int kk = 0; kk < 32; kk += 4) {
            const int k0 = kg * 32 + kk;
            const float4* r0p = Rg + (size_t)(k0 + 0) * 32;
            const float4* r1p = Rg + (size_t)(k0 + 1) * 32;
            const float4* r2p = Rg + (size_t)(k0 + 2) * 32;
            const float4* r3p = Rg + (size_t)(k0 + 3) * 32;
            float t0 = 0.f, t1 = 0.f, t2 = 0.f, t3 = 0.f;
#pragma unroll 8
            for (int c4 = 0; c4 < 32; ++c4) {
                const float4 hv = sh4[row * 33 + c4];
                const float4 r0 = r0p[c4];
                const float4 r1 = r1p[c4];
                const float4 r2 = r2p[c4];
                const float4 r3 = r3p[c4];
                t0 = fmaf(hv.x, r0.x, fmaf(hv.y, r0.y, fmaf(hv.z, r0.z, fmaf(hv.w, r0.w, t0))));
                t1 = fmaf(hv.x, r1.x, fmaf(hv.y, r1.y, fmaf(hv.z, r1.z, fmaf(hv.w, r1.w, t1))));
                t2 = fmaf(hv.x, r2.x, fmaf(hv.y, r2.y, fmaf(hv.z, r2.z, fmaf(hv.w, r2.w, t2))));
                t3 = fmaf(hv.x, r3.x, fmaf(hv.y, r3.y, fmaf(hv.z, r3.z, fmaf(hv.w, r3.w, t3))));
            }
            auto emit = [&](int j, float t) {
                float d2v = h2 + sh_r2[k0 + j] - 2.0f * t;
                float dist = sqrtf(fmaxf(d2v, 0.0f));
                float e = __expf(-ALPHA_F * dist);
                sh_e[row * 257 + k0 + j] = e;
                Spart += e;
            };
            emit(0, t0); emit(1, t1); emit(2, t2); emit(3, t3);
        }
        sh_sp[kg * 32 + row] = Spart;
    }
    __syncthreads();
    if (tid < ROWS) {
        float s = 0.f;
#pragma unroll
        for (int g = 0; g < 8; ++g) s += sh_sp[g * 32 + tid];
        sh_s[tid] = 1.0f / (s + EPS_F);
    }
    __syncthreads();

    // ---- phase 2: weighted centers + loss ----
    float lp = 0.f;
    {
        const int row = tid & 31, dg = tid >> 5;  // 8 dgroups x 16 d each
        const float4* Rg = (const float4*)R;
        float4 a0 = {0, 0, 0, 0}, a1 = {0, 0, 0, 0}, a2 = {0, 0, 0, 0}, a3 = {0, 0, 0, 0};
        const float* ep = sh_e + row * 257;
        for (int k = 0; k < KC; ++k) {
            const float e = ep[k];
            const float4* rp = Rg + (size_t)k * 32 + dg * 4;
            const float4 r0 = rp[0];
            const float4 r1 = rp[1];
            const float4 r2 = rp[2];
            const float4 r3 = rp[3];
            a0.x = fmaf(e, r0.x, a0.x); a0.y = fmaf(e, r0.y, a0.y);
            a0.z = fmaf(e, r0.z, a0.z); a0.w = fmaf(e, r0.w, a0.w);
            a1.x = fmaf(e, r1.x, a1.x); a1.y = fmaf(e, r1.y, a1.y);
            a1.z = fmaf(e, r1.z, a1.z); a1.w = fmaf(e, r1.w, a1.w);
            a2.x = fmaf(e, r2.x, a2.x); a2.y = fmaf(e, r2.y, a2.y);
            a2.z = fmaf(e, r2.z, a2.z); a2.w = fmaf(e, r2.w, a2.w);
            a3.x = fmaf(e, r3.x, a3.x); a3.y = fmaf(e, r3.y, a3.y);
            a3.z = fmaf(e, r3.z, a3.z); a3.w = fmaf(e, r3.w, a3.w);
        }
        const float inv = sh_s[row];
        const float* hp = sh_h + row * 132 + dg * 16;
        float df;
        df = hp[0]  - a0.x * inv; lp = fmaf(df, df, lp);
        df = hp[1]  - a0.y * inv; lp = fmaf(df, df, lp);
        df = hp[2]  - a0.z * inv; lp = fmaf(df, df, lp);
        df = hp[3]  - a0.w * inv; lp = fmaf(df, df, lp);
        df = hp[4]  - a1.x * inv; lp = fmaf(df, df, lp);
        df = hp[5]  - a1.y * inv; lp = fmaf(df, df, lp);
        df = hp[6]  - a1.z * inv; lp = fmaf(df, df, lp);
        df = hp[7]  - a1.w * inv; lp = fmaf(df, df, lp);
        df = hp[8]  - a2.x * inv; lp = fmaf(df, df, lp);
        df = hp[9]  - a2.y * inv; lp = fmaf(df, df, lp);
        df = hp[10] - a2.z * inv; lp = fmaf(df, df, lp);
        df = hp[11] - a2.w * inv; lp = fmaf(df, df, lp);
        df = hp[12] - a3.x * inv; lp = fmaf(df, df, lp);
        df = hp[13] - a3.y * inv; lp = fmaf(df, df, lp);
        df = hp[14] - a3.z * inv; lp = fmaf(df, df, lp);
        df = hp[15] - a3.w * inv; lp = fmaf(df, df, lp);
    }
    for (int off = 32; off > 0; off >>= 1) lp += __shfl_down(lp, off);
    const int lane = tid & 63, wv = tid >> 6;
    if (lane == 0) sw[wv] = lp;
    __syncthreads();
    if (tid == 0) partials[blockIdx.x] = sw[0] + sw[1] + sw[2] + sw[3];
}

// ---------------------------------------------------------------------------
// Kernel 3: final reduction + means.
// ---------------------------------------------------------------------------
__global__ __launch_bounds__(256) void finalize_kernel(const float* __restrict__ pr,
                                                       const float* __restrict__ pc,
                                                       float* __restrict__ out) {
    const int tid = threadIdx.x;
    float a = 0.f, b = 0.f;
    for (int i = tid; i < 2048; i += 256) a += pr[i];
    for (int i = tid; i < 512; i += 256) b += pc[i];
    float v = a * (1.0f / ((float)N_ROWS * (float)D_INP)) +
              b * (1.0f / ((float)N_ROWS * (float)D_LAT));
    for (int off = 32; off > 0; off >>= 1) v += __shfl_down(v, off);
    __shared__ float sw[4];
    if ((tid & 63) == 0) sw[tid >> 6] = v;
    __syncthreads();
    if (tid == 0) out[0] = sw[0] + sw[1] + sw[2] + sw[3];
}

extern "C" void kernel_launch(void* const* d_in, const int* in_sizes, int n_in,
                              void* d_out, int out_size, void* d_ws, size_t ws_size,
                              hipStream_t stream) {
    const float* x = (const float*)d_in[0];
    const float* h = (const float*)d_in[1];
    const float* a = (const float*)d_in[2];
    const float* R = (const float*)d_in[3];
    float* out = (float*)d_out;
    float* ws = (float*)d_ws;
    float* pr = ws;          // 2048 recon partials
    float* pc = ws + 2048;   // 512 cluster partials

    recon_kernel<<<2048, 256, 0, stream>>>(x, a, pr);
    cluster_kernel<<<512, 256, 0, stream>>>(h, R, pc);
    finalize_kernel<<<1, 256, 0, stream>>>(pr, pc, out);
}

// Round 2
// 73.189 us; speedup vs baseline: 2.1565x; 2.1565x over previous
//
#include <hip/hip_runtime.h>
#include <math.h>

#define N_ROWS 16384
#define D_INP  1024
#define D_LAT  128
#define KC     256
#define ALPHA_F 1.0f
#define EPS_F   1e-8f

typedef __attribute__((ext_vector_type(8))) short short8v;   // 8 bf16 (4 VGPR)
typedef __attribute__((ext_vector_type(4))) float floatx4;   // mfma C/D

__device__ __forceinline__ unsigned short f2bf(float f) {
    unsigned u = __float_as_uint(f);
    return (unsigned short)((u + 0x7FFFu + ((u >> 16) & 1u)) >> 16);  // RNE
}
__device__ __forceinline__ float bf2f(unsigned short b) {
    return __uint_as_float(((unsigned)b) << 16);
}

// ---------------------------------------------------------------------------
// Prep: bf16 hi/lo split of R, row-major (Rb) and transposed (Rt), plus r2[k].
// Block b handles centers 2b, 2b+1 (128 threads each).
// ---------------------------------------------------------------------------
__global__ __launch_bounds__(256) void prep_kernel(const float* __restrict__ R,
        unsigned short* __restrict__ Rb_hi, unsigned short* __restrict__ Rb_lo,
        unsigned short* __restrict__ Rt_hi, unsigned short* __restrict__ Rt_lo,
        float* __restrict__ r2) {
    const int t = threadIdx.x;
    const int kc = blockIdx.x * 2 + (t >> 7);
    const int d = t & 127;
    const float v = R[kc * D_LAT + d];
    const unsigned short hi = f2bf(v);
    const unsigned short lo = f2bf(v - bf2f(hi));
    Rb_hi[kc * D_LAT + d] = hi;
    Rb_lo[kc * D_LAT + d] = lo;
    Rt_hi[d * KC + kc] = hi;
    Rt_lo[d * KC + kc] = lo;
    float sq = v * v;
    for (int off = 32; off > 0; off >>= 1) sq += __shfl_down(sq, off);
    __shared__ float s4[4];
    if ((t & 63) == 0) s4[t >> 6] = sq;
    __syncthreads();
    if (t == 0)   r2[kc] = s4[0] + s4[1];
    if (t == 128) r2[kc] = s4[2] + s4[3];
}

// ---------------------------------------------------------------------------
// Recon MSE partials (unchanged; memory-bound, fine).
// ---------------------------------------------------------------------------
__global__ __launch_bounds__(256) void recon_kernel(const float* __restrict__ x,
                                                    const float* __restrict__ a,
                                                    float* __restrict__ partials) {
    const int tid = threadIdx.x;
    const int gid = blockIdx.x * 256 + tid;
    const int stride = gridDim.x * 256;
    const int n4 = (N_ROWS * D_INP) / 4;
    const float4* x4 = (const float4*)x;
    const float4* a4 = (const float4*)a;
    float acc = 0.f;
    for (int i = gid; i < n4; i += stride) {
        float4 xv = x4[i];
        float4 av = a4[i];
        float d0 = xv.x - av.x, d1 = xv.y - av.y, d2 = xv.z - av.z, d3 = xv.w - av.w;
        acc = fmaf(d0, d0, acc);
        acc = fmaf(d1, d1, acc);
        acc = fmaf(d2, d2, acc);
        acc = fmaf(d3, d3, acc);
    }
    for (int off = 32; off > 0; off >>= 1) acc += __shfl_down(acc, off);
    __shared__ float sw[4];
    if ((tid & 63) == 0) sw[tid >> 6] = acc;
    __syncthreads();
    if (tid == 0) partials[blockIdx.x] = sw[0] + sw[1] + sw[2] + sw[3];
}

// ---------------------------------------------------------------------------
// Cluster loss via MFMA. 32 rows/block, 8 waves (512 thr), 512 blocks.
// Phase A: S = h.R^T (split-bf16, 3 mfma) -> e = exp(-dist), row sums,
//          e (bf16) stored to LDS in A-fragment order.
// Phase B: wc_un = E.R (E_hi x Rt_hi/lo), normalize fp32, loss partials.
// k-slot mapping k = ks*32 + g*8 + j is fed IDENTICALLY to A and B operands,
// so any discrepancy vs the HW's internal k-order cancels in the dot product.
// ---------------------------------------------------------------------------
__global__ __launch_bounds__(512) void cluster_mfma_kernel(
        const float* __restrict__ h,
        const unsigned short* __restrict__ Rb_hi, const unsigned short* __restrict__ Rb_lo,
        const unsigned short* __restrict__ Rt_hi, const unsigned short* __restrict__ Rt_lo,
        const float* __restrict__ r2w, float* __restrict__ partials) {
    const int tid = threadIdx.x;
    const int wv = tid >> 6;         // 0..7
    const int lane = tid & 63;
    const int g = lane >> 4;         // 0..3 : k-group (A/B), row-group (C/D)
    const int c = lane & 15;         // A row / B col / C col
    const int rbase = blockIdx.x * 32;

    __shared__ unsigned short eL[2 * 32 * 16 * 8];  // [s][kgrp][m][j], 16 KiB
    __shared__ float h2L[32];
    __shared__ float sumsL[32][8];
    __shared__ float invL[32];
    __shared__ float swL[8];

    float rs[2][4] = {{0.f, 0.f, 0.f, 0.f}, {0.f, 0.f, 0.f, 0.f}};

    // ---------------- Phase A ----------------
#pragma unroll
    for (int s = 0; s < 2; ++s) {
        const int row = rbase + s * 16 + c;
        const float* hrow = h + (size_t)row * D_LAT;
        short8v ahi[4], alo[4];
        float h2p = 0.f;
#pragma unroll
        for (int ks = 0; ks < 4; ++ks) {
            const float4 q0 = *(const float4*)(hrow + ks * 32 + g * 8);
            const float4 q1 = *(const float4*)(hrow + ks * 32 + g * 8 + 4);
            const float vals[8] = {q0.x, q0.y, q0.z, q0.w, q1.x, q1.y, q1.z, q1.w};
            short8v vh, vl;
#pragma unroll
            for (int j = 0; j < 8; ++j) {
                const float v = vals[j];
                const unsigned short hi = f2bf(v);
                vh[j] = (short)hi;
                vl[j] = (short)f2bf(v - bf2f(hi));
                h2p = fmaf(v, v, h2p);
            }
            ahi[ks] = vh;
            alo[ks] = vl;
        }
        h2p += __shfl_xor(h2p, 16);
        h2p += __shfl_xor(h2p, 32);
        if (g == 0) h2L[s * 16 + c] = h2p;  // each wave writes all 16 rows itself

#pragma unroll
        for (int tt = 0; tt < 2; ++tt) {
            const int ct = wv * 2 + tt;          // 16 col-tiles over 8 waves
            const int kc = ct * 16 + c;
            floatx4 acc = {0.f, 0.f, 0.f, 0.f};
#pragma unroll
            for (int ks = 0; ks < 4; ++ks) {
                const size_t ro = (size_t)kc * D_LAT + ks * 32 + g * 8;
                const short8v bhi = *(const short8v*)(Rb_hi + ro);
                const short8v blo = *(const short8v*)(Rb_lo + ro);
                acc = __builtin_amdgcn_mfma_f32_16x16x32_bf16(ahi[ks], bhi, acc, 0, 0, 0);
                acc = __builtin_amdgcn_mfma_f32_16x16x32_bf16(ahi[ks], blo, acc, 0, 0, 0);
                acc = __builtin_amdgcn_mfma_f32_16x16x32_bf16(alo[ks], bhi, acc, 0, 0, 0);
            }
            const float r2v = r2w[kc];
            const float4 hq = *(const float4*)&h2L[s * 16 + 4 * g];
            const float hqa[4] = {hq.x, hq.y, hq.z, hq.w};
#pragma unroll
            for (int i = 0; i < 4; ++i) {
                const float d2 = hqa[i] + r2v - 2.0f * acc[i];
                const float dist = sqrtf(fmaxf(d2, 0.f));
                const float e = __expf(-ALPHA_F * dist);
                rs[s][i] += e;
                eL[(((size_t)s * 32 + (kc >> 3)) * 16 + (4 * g + i)) * 8 + (kc & 7)] = f2bf(e);
            }
        }
    }
    // row-sum reduce across the 16 c-lanes
#pragma unroll
    for (int s = 0; s < 2; ++s)
#pragma unroll
        for (int i = 0; i < 4; ++i) {
            float v = rs[s][i];
            v += __shfl_xor(v, 1);
            v += __shfl_xor(v, 2);
            v += __shfl_xor(v, 4);
            v += __shfl_xor(v, 8);
            if (c == 0) sumsL[s * 16 + 4 * g + i][wv] = v;
        }
    __syncthreads();
    if (tid < 32) {
        float tot = 0.f;
#pragma unroll
        for (int w = 0; w < 8; ++w) tot += sumsL[tid][w];
        invL[tid] = 1.0f / (tot + EPS_F);
    }
    __syncthreads();

    // ---------------- Phase B ----------------
    const int sB = wv & 1;
    const int dtbase = (wv >> 1) * 2;   // 8 d-tiles over 4 wave-pairs
    short8v aE[8];
#pragma unroll
    for (int ks = 0; ks < 8; ++ks)
        aE[ks] = *(const short8v*)&eL[(((size_t)sB * 32 + ks * 4 + g) * 16 + c) * 8];
    const float4 inv4 = *(const float4*)&invL[sB * 16 + 4 * g];
    const float inva[4] = {inv4.x, inv4.y, inv4.z, inv4.w};
    float lp = 0.f;
#pragma unroll
    for (int tt = 0; tt < 2; ++tt) {
        const int dcol = (dtbase + tt) * 16 + c;
        floatx4 acc = {0.f, 0.f, 0.f, 0.f};
#pragma unroll
        for (int ks = 0; ks < 8; ++ks) {
            const size_t ro = (size_t)dcol * KC + ks * 32 + g * 8;
            const short8v bhi = *(const short8v*)(Rt_hi + ro);
            const short8v blo = *(const short8v*)(Rt_lo + ro);
            acc = __builtin_amdgcn_mfma_f32_16x16x32_bf16(aE[ks], bhi, acc, 0, 0, 0);
            acc = __builtin_amdgcn_mfma_f32_16x16x32_bf16(aE[ks], blo, acc, 0, 0, 0);
        }
#pragma unroll
        for (int i = 0; i < 4; ++i) {
            const int row = rbase + sB * 16 + 4 * g + i;
            const float wc = acc[i] * inva[i];
            const float hv = h[(size_t)row * D_LAT + dcol];
            const float df = hv - wc;
            lp = fmaf(df, df, lp);
        }
    }
    for (int off = 32; off > 0; off >>= 1) lp += __shfl_down(lp, off);
    if (lane == 0) swL[wv] = lp;
    __syncthreads();
    if (tid == 0) {
        float t = 0.f;
#pragma unroll
        for (int w = 0; w < 8; ++w) t += swL[w];
        partials[blockIdx.x] = t;
    }
}

// ---------------------------------------------------------------------------
// Final reduction + means.
// ---------------------------------------------------------------------------
__global__ __launch_bounds__(256) void finalize_kernel(const float* __restrict__ pr,
                                                       const float* __restrict__ pc,
                                                       float* __restrict__ out) {
    const int tid = threadIdx.x;
    float a = 0.f, b = 0.f;
    for (int i = tid; i < 2048; i += 256) a += pr[i];
    for (int i = tid; i < 512; i += 256) b += pc[i];
    float v = a * (1.0f / ((float)N_ROWS * (float)D_INP)) +
              b * (1.0f / ((float)N_ROWS * (float)D_LAT));
    for (int off = 32; off > 0; off >>= 1) v += __shfl_down(v, off);
    __shared__ float sw[4];
    if ((tid & 63) == 0) sw[tid >> 6] = v;
    __syncthreads();
    if (tid == 0) out[0] = sw[0] + sw[1] + sw[2] + sw[3];
}

extern "C" void kernel_launch(void* const* d_in, const int* in_sizes, int n_in,
                              void* d_out, int out_size, void* d_ws, size_t ws_size,
                              hipStream_t stream) {
    const float* x = (const float*)d_in[0];
    const float* h = (const float*)d_in[1];
    const float* a = (const float*)d_in[2];
    const float* R = (const float*)d_in[3];
    float* out = (float*)d_out;
    char* wsb = (char*)d_ws;
    float* pr = (float*)(wsb + 0);              // 2048 f
    float* pc = (float*)(wsb + 8192);           // 512 f
    float* r2 = (float*)(wsb + 10240);          // 256 f
    unsigned short* Rb_hi = (unsigned short*)(wsb + 12288);
    unsigned short* Rb_lo = (unsigned short*)(wsb + 12288 + 65536);
    unsigned short* Rt_hi = (unsigned short*)(wsb + 12288 + 2 * 65536);
    unsigned short* Rt_lo = (unsigned short*)(wsb + 12288 + 3 * 65536);

    prep_kernel<<<128, 256, 0, stream>>>(R, Rb_hi, Rb_lo, Rt_hi, Rt_lo, r2);
    recon_kernel<<<2048, 256, 0, stream>>>(x, a, pr);
    cluster_mfma_kernel<<<512, 512, 0, stream>>>(h, Rb_hi, Rb_lo, Rt_hi, Rt_lo, r2, pc);
    finalize_kernel<<<1, 256, 0, stream>>>(pr, pc, out);
}

// Round 3
// 47.390 us; speedup vs baseline: 3.3305x; 1.5444x over previous
//
#include <hip/hip_runtime.h>
#include <math.h>

#define N_ROWS 16384
#define D_INP  1024
#define D_LAT  128
#define KC     256
#define EPS_F  1e-8f

typedef __attribute__((ext_vector_type(8))) short short8v;   // 8 bf16
typedef _Float16 half8v __attribute__((ext_vector_type(8))); // 8 fp16
typedef __attribute__((ext_vector_type(4))) float floatx4;   // mfma C/D

__device__ __forceinline__ unsigned short f2bf(float f) {
    unsigned u = __float_as_uint(f);
    return (unsigned short)((u + 0x7FFFu + ((u >> 16) & 1u)) >> 16);  // RNE
}
__device__ __forceinline__ unsigned short f2h(float f) {
    _Float16 h = (_Float16)f;
    unsigned short u;
    __builtin_memcpy(&u, &h, 2);
    return u;
}

// ---------------------------------------------------------------------------
// Prep: R -> fp16 row-major (phase A B-operand), bf16 transposed (phase B),
// plus r2[k].  Block b handles centers 2b, 2b+1.
// ---------------------------------------------------------------------------
__global__ __launch_bounds__(256) void prep_kernel(const float* __restrict__ R,
        unsigned short* __restrict__ Rf16, unsigned short* __restrict__ Rtb,
        float* __restrict__ r2) {
    const int t = threadIdx.x;
    const int kc = blockIdx.x * 2 + (t >> 7);
    const int d = t & 127;
    const float v = R[kc * D_LAT + d];
    Rf16[kc * D_LAT + d] = f2h(v);
    Rtb[d * KC + kc] = f2bf(v);
    float sq = v * v;
    for (int off = 32; off > 0; off >>= 1) sq += __shfl_down(sq, off);
    __shared__ float s4[4];
    if ((t & 63) == 0) s4[t >> 6] = sq;
    __syncthreads();
    if (t == 0)   r2[kc] = s4[0] + s4[1];
    if (t == 128) r2[kc] = s4[2] + s4[3];
}

// ---------------------------------------------------------------------------
// Fused kernel, 3072 blocks x 512 threads.
//   bid%3==0 : cluster block (cid = bid/3, 16 rows)       -- 1024 blocks
//   else     : recon block (rid = bid-1-bid/3, streaming) -- 2048 blocks
// Interleaving puts ~1 cluster + 2 recon blocks per CU slot so the
// memory-bound recon stream hides cluster's L2-latency stalls.
// ---------------------------------------------------------------------------
__global__ __launch_bounds__(512, 8) void fused_kernel(
        const float* __restrict__ x, const float* __restrict__ a,
        const float* __restrict__ h,
        const unsigned short* __restrict__ Rf16,
        const unsigned short* __restrict__ Rtb,
        const float* __restrict__ r2w,
        float* __restrict__ pr, float* __restrict__ pc) {
    __shared__ float sh32[16 * 132];          // h fp32, row stride 132 (bank-spread)
    __shared__ unsigned short sh16[16 * 136]; // h fp16, row stride 136
    __shared__ unsigned short eL[16 * 264];   // e bf16, row stride 264
    __shared__ float sumsL[16][16];
    __shared__ float h2L[16];
    __shared__ float invL[16];
    __shared__ float swL[8];

    const int bid = blockIdx.x;
    const int tid = threadIdx.x;

    if (bid % 3 != 0) {
        // ---------------- recon ----------------
        const int rid = bid - 1 - bid / 3;               // 0..2047
        const int gid = rid * 512 + tid;                 // 1,048,576 threads
        const float4* x4 = (const float4*)x;
        const float4* a4 = (const float4*)a;
        float acc = 0.f;
#pragma unroll
        for (int it = 0; it < 4; ++it) {                 // 8 loads in flight
            const int i = gid + it * (512 * 2048);
            const float4 xv = x4[i];
            const float4 av = a4[i];
            const float d0 = xv.x - av.x, d1 = xv.y - av.y;
            const float d2 = xv.z - av.z, d3 = xv.w - av.w;
            acc = fmaf(d0, d0, acc);
            acc = fmaf(d1, d1, acc);
            acc = fmaf(d2, d2, acc);
            acc = fmaf(d3, d3, acc);
        }
        for (int off = 32; off > 0; off >>= 1) acc += __shfl_down(acc, off);
        if ((tid & 63) == 0) swL[tid >> 6] = acc;
        __syncthreads();
        if (tid == 0) {
            float t = 0.f;
#pragma unroll
            for (int w = 0; w < 8; ++w) t += swL[w];
            pr[rid] = t;
        }
        return;
    }

    // ---------------- cluster ----------------
    const int cid = bid / 3;                 // 0..1023
    const int rbase = cid * 16;
    const int wv = tid >> 6, lane = tid & 63;
    const int g = lane >> 4, c = lane & 15;

    // stage h: 512 threads x 1 float4 = 16 rows x 128 cols; convert to fp16;
    // per-row |h|^2 via 32-lane shfl reduce.
    {
        const int r = tid >> 5, c4 = tid & 31;
        const float4 v = *(const float4*)(h + (size_t)(rbase + r) * D_LAT + c4 * 4);
        *(float4*)&sh32[r * 132 + c4 * 4] = v;
        sh16[r * 136 + c4 * 4 + 0] = f2h(v.x);
        sh16[r * 136 + c4 * 4 + 1] = f2h(v.y);
        sh16[r * 136 + c4 * 4 + 2] = f2h(v.z);
        sh16[r * 136 + c4 * 4 + 3] = f2h(v.w);
        float s = v.x * v.x + v.y * v.y + v.z * v.z + v.w * v.w;
        s += __shfl_xor(s, 1);
        s += __shfl_xor(s, 2);
        s += __shfl_xor(s, 4);
        s += __shfl_xor(s, 8);
        s += __shfl_xor(s, 16);
        if ((tid & 31) == 0) h2L[r] = s;
    }
    __syncthreads();

    // ---- phase A: S = h.R^T (fp16 mfma), e = exp(-dist), row sums ----
    half8v afr[4];
#pragma unroll
    for (int ks = 0; ks < 4; ++ks)
        afr[ks] = *(const half8v*)&sh16[c * 136 + ks * 32 + g * 8];
    float h2a[4];
#pragma unroll
    for (int i = 0; i < 4; ++i) h2a[i] = h2L[4 * g + i];

#pragma unroll
    for (int tt = 0; tt < 2; ++tt) {
        const int tile = wv * 2 + tt;        // 16 col-tiles over 8 waves
        const int kc = tile * 16 + c;
        floatx4 acc = {0.f, 0.f, 0.f, 0.f};
#pragma unroll
        for (int ks = 0; ks < 4; ++ks) {
            const half8v b = *(const half8v*)(Rf16 + (size_t)kc * D_LAT + ks * 32 + g * 8);
            acc = __builtin_amdgcn_mfma_f32_16x16x32_f16(afr[ks], b, acc, 0, 0, 0);
        }
        const float r2v = r2w[kc];
#pragma unroll
        for (int i = 0; i < 4; ++i) {
            const float d2 = h2a[i] + r2v - 2.0f * acc[i];
            const float e = __expf(-sqrtf(fmaxf(d2, 0.f)));
            eL[(4 * g + i) * 264 + kc] = f2bf(e);
            float v = e;                      // sum over the 16 kc of this tile
            v += __shfl_xor(v, 1);
            v += __shfl_xor(v, 2);
            v += __shfl_xor(v, 4);
            v += __shfl_xor(v, 8);
            if (c == 0) sumsL[4 * g + i][tile] = v;
        }
    }
    __syncthreads();
    if (tid < 16) {
        float t = 0.f;
#pragma unroll
        for (int j = 0; j < 16; ++j) t += sumsL[tid][j];
        invL[tid] = 1.0f / (t + EPS_F);
    }
    __syncthreads();

    // ---- phase B: wc = E.R (bf16 mfma), loss partials ----
    const int dcol = wv * 16 + c;            // 8 d-tiles over 8 waves
    float inva[4];
#pragma unroll
    for (int i = 0; i < 4; ++i) inva[i] = invL[4 * g + i];
    floatx4 acc = {0.f, 0.f, 0.f, 0.f};
#pragma unroll
    for (int ks = 0; ks < 8; ++ks) {
        const short8v ae = *(const short8v*)&eL[c * 264 + ks * 32 + g * 8];
        const short8v b = *(const short8v*)(Rtb + (size_t)dcol * KC + ks * 32 + g * 8);
        acc = __builtin_amdgcn_mfma_f32_16x16x32_bf16(ae, b, acc, 0, 0, 0);
    }
    float lp = 0.f;
#pragma unroll
    for (int i = 0; i < 4; ++i) {
        const float wc = acc[i] * inva[i];
        const float hv = sh32[(4 * g + i) * 132 + dcol];
        const float df = hv - wc;
        lp = fmaf(df, df, lp);
    }
    for (int off = 32; off > 0; off >>= 1) lp += __shfl_down(lp, off);
    if (lane == 0) swL[wv] = lp;
    __syncthreads();
    if (tid == 0) {
        float t = 0.f;
#pragma unroll
        for (int w = 0; w < 8; ++w) t += swL[w];
        pc[cid] = t;
    }
}

// ---------------------------------------------------------------------------
// Final reduction + means.
// ---------------------------------------------------------------------------
__global__ __launch_bounds__(256) void finalize_kernel(const float* __restrict__ pr,
                                                       const float* __restrict__ pc,
                                                       float* __restrict__ out) {
    const int tid = threadIdx.x;
    float a = 0.f, b = 0.f;
    for (int i = tid; i < 2048; i += 256) a += pr[i];
    for (int i = tid; i < 1024; i += 256) b += pc[i];
    float v = a * (1.0f / ((float)N_ROWS * (float)D_INP)) +
              b * (1.0f / ((float)N_ROWS * (float)D_LAT));
    for (int off = 32; off > 0; off >>= 1) v += __shfl_down(v, off);
    __shared__ float sw[4];
    if ((tid & 63) == 0) sw[tid >> 6] = v;
    __syncthreads();
    if (tid == 0) out[0] = sw[0] + sw[1] + sw[2] + sw[3];
}

extern "C" void kernel_launch(void* const* d_in, const int* in_sizes, int n_in,
                              void* d_out, int out_size, void* d_ws, size_t ws_size,
                              hipStream_t stream) {
    const float* x = (const float*)d_in[0];
    const float* h = (const float*)d_in[1];
    const float* a = (const float*)d_in[2];
    const float* R = (const float*)d_in[3];
    float* out = (float*)d_out;
    char* wsb = (char*)d_ws;
    float* pr = (float*)(wsb + 0);                       // 2048 f
    float* pc = (float*)(wsb + 8192);                    // 1024 f
    float* r2 = (float*)(wsb + 12288);                   // 256 f
    unsigned short* Rf16 = (unsigned short*)(wsb + 16384);          // 64 KiB
    unsigned short* Rtb  = (unsigned short*)(wsb + 16384 + 65536);  // 64 KiB

    prep_kernel<<<128, 256, 0, stream>>>(R, Rf16, Rtb, r2);
    fused_kernel<<<3072, 512, 0, stream>>>(x, a, h, Rf16, Rtb, r2, pr, pc);
    finalize_kernel<<<1, 256, 0, stream>>>(pr, pc, out);
}

// Round 4
// 46.209 us; speedup vs baseline: 3.4156x; 1.0255x over previous
//
#include <hip/hip_runtime.h>
#include <math.h>

#define N_ROWS 16384
#define D_INP  1024
#define D_LAT  128
#define KC     256
#define EPS_F  1e-8f

typedef __attribute__((ext_vector_type(8))) short short8v;   // 8 bf16
typedef _Float16 half8v __attribute__((ext_vector_type(8))); // 8 fp16
typedef __attribute__((ext_vector_type(4))) float floatx4;   // mfma C/D

__device__ __forceinline__ unsigned short f2bf(float f) {
    unsigned u = __float_as_uint(f);
    return (unsigned short)((u + 0x7FFFu + ((u >> 16) & 1u)) >> 16);  // RNE
}
__device__ __forceinline__ unsigned short f2h(float f) {
    _Float16 h = (_Float16)f;
    unsigned short u;
    __builtin_memcpy(&u, &h, 2);
    return u;
}

// ---------------------------------------------------------------------------
// Prep: R -> fp16 row-major (phase A B-operand), bf16 transposed (phase B),
// plus r2[k].  Block b handles centers 2b, 2b+1.
// ---------------------------------------------------------------------------
__global__ __launch_bounds__(256) void prep_kernel(const float* __restrict__ R,
        unsigned short* __restrict__ Rf16, unsigned short* __restrict__ Rtb,
        float* __restrict__ r2) {
    const int t = threadIdx.x;
    const int kc = blockIdx.x * 2 + (t >> 7);
    const int d = t & 127;
    const float v = R[kc * D_LAT + d];
    Rf16[kc * D_LAT + d] = f2h(v);
    Rtb[d * KC + kc] = f2bf(v);
    float sq = v * v;
    for (int off = 32; off > 0; off >>= 1) sq += __shfl_down(sq, off);
    __shared__ float s4[4];
    if ((t & 63) == 0) s4[t >> 6] = sq;
    __syncthreads();
    if (t == 0)   r2[kc] = s4[0] + s4[1];
    if (t == 128) r2[kc] = s4[2] + s4[3];
}

// ---------------------------------------------------------------------------
// Fused kernel, 2048 blocks x 512 threads.
//   bid odd  : recon block (rid = bid>>1), 8 float4-pairs per thread,
//              all 16 loads issued before any FMA -> deep MLP.
//   bid even : cluster block (cid = bid>>1, 16 rows).
// ---------------------------------------------------------------------------
__global__ __launch_bounds__(512) void fused_kernel(
        const float* __restrict__ x, const float* __restrict__ a,
        const float* __restrict__ h,
        const unsigned short* __restrict__ Rf16,
        const unsigned short* __restrict__ Rtb,
        const float* __restrict__ r2w,
        float* __restrict__ pr, float* __restrict__ pc) {
    __shared__ float sh32[16 * 132];          // h fp32, row stride 132
    __shared__ unsigned short sh16[16 * 136]; // h fp16, row stride 136
    __shared__ unsigned short eL[16 * 264];   // e bf16, row stride 264
    __shared__ float sumsL[16][16];
    __shared__ float h2L[16];
    __shared__ float invL[16];
    __shared__ float swL[8];

    const int bid = blockIdx.x;
    const int tid = threadIdx.x;

    if (bid & 1) {
        // ---------------- recon ----------------
        const int rid = bid >> 1;                        // 0..1023
        const int gid = rid * 512 + tid;                 // 524,288 threads
        const float4* x4 = (const float4*)x;
        const float4* a4 = (const float4*)a;
        float4 xv[8], av[8];
#pragma unroll
        for (int it = 0; it < 8; ++it) {                 // 16 loads in flight
            const int i = gid + it * (512 * 1024);
            xv[it] = x4[i];
            av[it] = a4[i];
        }
        float a0 = 0.f, a1 = 0.f, a2 = 0.f, a3 = 0.f;
#pragma unroll
        for (int it = 0; it < 8; ++it) {
            const float d0 = xv[it].x - av[it].x, d1 = xv[it].y - av[it].y;
            const float d2 = xv[it].z - av[it].z, d3 = xv[it].w - av[it].w;
            a0 = fmaf(d0, d0, a0);
            a1 = fmaf(d1, d1, a1);
            a2 = fmaf(d2, d2, a2);
            a3 = fmaf(d3, d3, a3);
        }
        float acc = (a0 + a1) + (a2 + a3);
        for (int off = 32; off > 0; off >>= 1) acc += __shfl_down(acc, off);
        if ((tid & 63) == 0) swL[tid >> 6] = acc;
        __syncthreads();
        if (tid == 0) {
            float t = 0.f;
#pragma unroll
            for (int w = 0; w < 8; ++w) t += swL[w];
            pr[rid] = t;
        }
        return;
    }

    // ---------------- cluster ----------------
    const int cid = bid >> 1;                // 0..1023
    const int rbase = cid * 16;
    const int wv = tid >> 6, lane = tid & 63;
    const int g = lane >> 4, c = lane & 15;

    // stage h: 512 threads x 1 float4 = 16 rows x 128 cols; convert to fp16;
    // per-row |h|^2 via 32-lane shfl reduce.
    {
        const int r = tid >> 5, c4 = tid & 31;
        const float4 v = *(const float4*)(h + (size_t)(rbase + r) * D_LAT + c4 * 4);
        *(float4*)&sh32[r * 132 + c4 * 4] = v;
        sh16[r * 136 + c4 * 4 + 0] = f2h(v.x);
        sh16[r * 136 + c4 * 4 + 1] = f2h(v.y);
        sh16[r * 136 + c4 * 4 + 2] = f2h(v.z);
        sh16[r * 136 + c4 * 4 + 3] = f2h(v.w);
        float s = v.x * v.x + v.y * v.y + v.z * v.z + v.w * v.w;
        s += __shfl_xor(s, 1);
        s += __shfl_xor(s, 2);
        s += __shfl_xor(s, 4);
        s += __shfl_xor(s, 8);
        s += __shfl_xor(s, 16);
        if ((tid & 31) == 0) h2L[r] = s;
    }
    __syncthreads();

    // ---- phase A: S = h.R^T (fp16 mfma), e = exp(-dist), row sums ----
    half8v afr[4];
#pragma unroll
    for (int ks = 0; ks < 4; ++ks)
        afr[ks] = *(const half8v*)&sh16[c * 136 + ks * 32 + g * 8];
    float h2a[4];
#pragma unroll
    for (int i = 0; i < 4; ++i) h2a[i] = h2L[4 * g + i];

#pragma unroll
    for (int tt = 0; tt < 2; ++tt) {
        const int tile = wv * 2 + tt;        // 16 col-tiles over 8 waves
        const int kc = tile * 16 + c;
        floatx4 acc = {0.f, 0.f, 0.f, 0.f};
#pragma unroll
        for (int ks = 0; ks < 4; ++ks) {
            const half8v b = *(const half8v*)(Rf16 + (size_t)kc * D_LAT + ks * 32 + g * 8);
            acc = __builtin_amdgcn_mfma_f32_16x16x32_f16(afr[ks], b, acc, 0, 0, 0);
        }
        const float r2v = r2w[kc];
#pragma unroll
        for (int i = 0; i < 4; ++i) {
            const float d2 = h2a[i] + r2v - 2.0f * acc[i];
            const float e = __expf(-sqrtf(fmaxf(d2, 0.f)));
            eL[(4 * g + i) * 264 + kc] = f2bf(e);
            float v = e;                      // sum over the 16 kc of this tile
            v += __shfl_xor(v, 1);
            v += __shfl_xor(v, 2);
            v += __shfl_xor(v, 4);
            v += __shfl_xor(v, 8);
            if (c == 0) sumsL[4 * g + i][tile] = v;
        }
    }
    __syncthreads();
    if (tid < 16) {
        float t = 0.f;
#pragma unroll
        for (int j = 0; j < 16; ++j) t += sumsL[tid][j];
        invL[tid] = 1.0f / (t + EPS_F);
    }
    __syncthreads();

    // ---- phase B: wc = E.R (bf16 mfma), loss partials ----
    const int dcol = wv * 16 + c;            // 8 d-tiles over 8 waves
    float inva[4];
#pragma unroll
    for (int i = 0; i < 4; ++i) inva[i] = invL[4 * g + i];
    floatx4 acc = {0.f, 0.f, 0.f, 0.f};
#pragma unroll
    for (int ks = 0; ks < 8; ++ks) {
        const short8v ae = *(const short8v*)&eL[c * 264 + ks * 32 + g * 8];
        const short8v b = *(const short8v*)(Rtb + (size_t)dcol * KC + ks * 32 + g * 8);
        acc = __builtin_amdgcn_mfma_f32_16x16x32_bf16(ae, b, acc, 0, 0, 0);
    }
    float lp = 0.f;
#pragma unroll
    for (int i = 0; i < 4; ++i) {
        const float wc = acc[i] * inva[i];
        const float hv = sh32[(4 * g + i) * 132 + dcol];
        const float df = hv - wc;
        lp = fmaf(df, df, lp);
    }
    for (int off = 32; off > 0; off >>= 1) lp += __shfl_down(lp, off);
    if (lane == 0) swL[wv] = lp;
    __syncthreads();
    if (tid == 0) {
        float t = 0.f;
#pragma unroll
        for (int w = 0; w < 8; ++w) t += swL[w];
        pc[cid] = t;
    }
}

// ---------------------------------------------------------------------------
// Final reduction + means.
// ---------------------------------------------------------------------------
__global__ __launch_bounds__(256) void finalize_kernel(const float* __restrict__ pr,
                                                       const float* __restrict__ pc,
                                                       float* __restrict__ out) {
    const int tid = threadIdx.x;
    float a = 0.f, b = 0.f;
    for (int i = tid; i < 1024; i += 256) a += pr[i];
    for (int i = tid; i < 1024; i += 256) b += pc[i];
    float v = a * (1.0f / ((float)N_ROWS * (float)D_INP)) +
              b * (1.0f / ((float)N_ROWS * (float)D_LAT));
    for (int off = 32; off > 0; off >>= 1) v += __shfl_down(v, off);
    __shared__ float sw[4];
    if ((tid & 63) == 0) sw[tid >> 6] = v;
    __syncthreads();
    if (tid == 0) out[0] = sw[0] + sw[1] + sw[2] + sw[3];
}

extern "C" void kernel_launch(void* const* d_in, const int* in_sizes, int n_in,
                              void* d_out, int out_size, void* d_ws, size_t ws_size,
                              hipStream_t stream) {
    const float* x = (const float*)d_in[0];
    const float* h = (const float*)d_in[1];
    const float* a = (const float*)d_in[2];
    const float* R = (const float*)d_in[3];
    float* out = (float*)d_out;
    char* wsb = (char*)d_ws;
    float* pr = (float*)(wsb + 0);                       // 1024 f
    float* pc = (float*)(wsb + 8192);                    // 1024 f
    float* r2 = (float*)(wsb + 12288);                   // 256 f
    unsigned short* Rf16 = (unsigned short*)(wsb + 16384);          // 64 KiB
    unsigned short* Rtb  = (unsigned short*)(wsb + 16384 + 65536);  // 64 KiB

    prep_kernel<<<128, 256, 0, stream>>>(R, Rf16, Rtb, r2);
    fused_kernel<<<2048, 512, 0, stream>>>(x, a, h, Rf16, Rtb, r2, pr, pc);
    finalize_kernel<<<1, 256, 0, stream>>>(pr, pc, out);
}

// Round 5
// 46.151 us; speedup vs baseline: 3.4199x; 1.0013x over previous
//
#include <hip/hip_runtime.h>
#include <math.h>

#define N_ROWS 16384
#define D_INP  1024
#define D_LAT  128
#define KC     256
#define EPS_F  1e-8f

typedef __attribute__((ext_vector_type(8))) short short8v;   // 8 bf16
typedef _Float16 half8v __attribute__((ext_vector_type(8))); // 8 fp16
typedef __attribute__((ext_vector_type(4))) float floatx4;   // mfma C/D

__device__ __forceinline__ unsigned short f2bf(float f) {
    unsigned u = __float_as_uint(f);
    return (unsigned short)((u + 0x7FFFu + ((u >> 16) & 1u)) >> 16);  // RNE
}
__device__ __forceinline__ unsigned short f2h(float f) {
    _Float16 h = (_Float16)f;
    unsigned short u;
    __builtin_memcpy(&u, &h, 2);
    return u;
}
__device__ __forceinline__ void gll16(const void* g, void* l) {
    __builtin_amdgcn_global_load_lds(
        (const __attribute__((address_space(1))) void*)g,
        (__attribute__((address_space(3))) void*)l, 16, 0, 0);
}

// ---------------------------------------------------------------------------
// Prep: R -> fp16 row-major (phase A B-operand), bf16 transposed (phase B),
// plus r2[k].  Block b handles centers 2b, 2b+1.
// ---------------------------------------------------------------------------
__global__ __launch_bounds__(256) void prep_kernel(const float* __restrict__ R,
        unsigned short* __restrict__ Rf16, unsigned short* __restrict__ Rtb,
        float* __restrict__ r2) {
    const int t = threadIdx.x;
    const int kc = blockIdx.x * 2 + (t >> 7);
    const int d = t & 127;
    const float v = R[kc * D_LAT + d];
    Rf16[kc * D_LAT + d] = f2h(v);
    Rtb[d * KC + kc] = f2bf(v);
    float sq = v * v;
    for (int off = 32; off > 0; off >>= 1) sq += __shfl_down(sq, off);
    __shared__ float s4[4];
    if ((t & 63) == 0) s4[t >> 6] = sq;
    __syncthreads();
    if (t == 0)   r2[kc] = s4[0] + s4[1];
    if (t == 128) r2[kc] = s4[2] + s4[3];
}

// ---------------------------------------------------------------------------
// Fused kernel, 2048 blocks x 512 threads, 48KB LDS arena (3 blocks/CU).
//   bid odd  : recon block (rid = bid>>1). Per wave: 8 chunks of
//              (1KB x + 1KB a) streamed through a 3-deep global_load_lds
//              pipeline with counted vmcnt — no barrier (each lane reads
//              back only its own 16B), so loads stay in flight.
//   bid even : cluster block (cid = bid>>1, 16 rows), MFMA path.
// ---------------------------------------------------------------------------
__global__ __launch_bounds__(512) void fused_kernel(
        const float* __restrict__ x, const float* __restrict__ a,
        const float* __restrict__ h,
        const unsigned short* __restrict__ Rf16,
        const unsigned short* __restrict__ Rtb,
        const float* __restrict__ r2w,
        float* __restrict__ pr, float* __restrict__ pc) {
    __shared__ __align__(16) char arena[49152];  // 8 waves * 3 slots * 2KB
    __shared__ float rsw[8];

    const int bid = blockIdx.x;
    const int tid = threadIdx.x;
    const int wv = tid >> 6, lane = tid & 63;

    if (bid & 1) {
        // ---------------- recon ----------------
        const int rid = bid >> 1;                        // 0..1023
        const float4* xg = (const float4*)x + (size_t)rid * 4096 + wv * 512 + lane;
        const float4* ag = (const float4*)a + (size_t)rid * 4096 + wv * 512 + lane;
        char* slot = arena + wv * 6144;
        float a0 = 0.f, a1 = 0.f, a2 = 0.f, a3 = 0.f;

#define ISSUE(j) do { \
            gll16(xg + (j) * 64, slot + ((j) % 3) * 2048); \
            gll16(ag + (j) * 64, slot + ((j) % 3) * 2048 + 1024); \
        } while (0)
#define WAITVM(n) asm volatile("s_waitcnt vmcnt(" #n ")" ::: "memory")
#define LGKM0()   asm volatile("s_waitcnt lgkmcnt(0)" ::: "memory")
#define CONSUME(j) do { \
            const float4 xv = *(const float4*)(slot + ((j) % 3) * 2048 + lane * 16); \
            const float4 av = *(const float4*)(slot + ((j) % 3) * 2048 + 1024 + lane * 16); \
            const float d0 = xv.x - av.x, d1 = xv.y - av.y; \
            const float d2 = xv.z - av.z, d3 = xv.w - av.w; \
            a0 = fmaf(d0, d0, a0); a1 = fmaf(d1, d1, a1); \
            a2 = fmaf(d2, d2, a2); a3 = fmaf(d3, d3, a3); \
        } while (0)

        ISSUE(0); ISSUE(1); ISSUE(2);
        WAITVM(4); CONSUME(0); LGKM0(); ISSUE(3);
        WAITVM(4); CONSUME(1); LGKM0(); ISSUE(4);
        WAITVM(4); CONSUME(2); LGKM0(); ISSUE(5);
        WAITVM(4); CONSUME(3); LGKM0(); ISSUE(6);
        WAITVM(4); CONSUME(4); LGKM0(); ISSUE(7);
        WAITVM(4); CONSUME(5);
        WAITVM(2); CONSUME(6);
        WAITVM(0); CONSUME(7);
#undef ISSUE
#undef WAITVM
#undef LGKM0
#undef CONSUME

        float acc = (a0 + a1) + (a2 + a3);
        for (int off = 32; off > 0; off >>= 1) acc += __shfl_down(acc, off);
        if (lane == 0) rsw[wv] = acc;
        __syncthreads();
        if (tid == 0) {
            float t = 0.f;
#pragma unroll
            for (int w = 0; w < 8; ++w) t += rsw[w];
            pr[rid] = t;
        }
        return;
    }

    // ---------------- cluster (LDS arrays unioned into arena) ----------------
    float* sh32          = (float*)(arena);                  // 16*132 f, 8448 B
    unsigned short* sh16 = (unsigned short*)(arena + 8448);  // 16*136 h, 4352 B
    unsigned short* eLp  = (unsigned short*)(arena + 12800); // 16*264 bf, 8448 B
    float (*sumsL)[16]   = (float(*)[16])(arena + 21248);    // 1024 B
    float* h2L           = (float*)(arena + 22272);          // 64 B
    float* invL          = (float*)(arena + 22336);          // 64 B
    float* swL           = (float*)(arena + 22400);          // 32 B

    const int cid = bid >> 1;                // 0..1023
    const int rbase = cid * 16;
    const int g = lane >> 4, c = lane & 15;

    // stage h: 512 threads x 1 float4 = 16 rows x 128 cols; convert to fp16;
    // per-row |h|^2 via 32-lane shfl reduce.
    {
        const int r = tid >> 5, c4 = tid & 31;
        const float4 v = *(const float4*)(h + (size_t)(rbase + r) * D_LAT + c4 * 4);
        *(float4*)&sh32[r * 132 + c4 * 4] = v;
        sh16[r * 136 + c4 * 4 + 0] = f2h(v.x);
        sh16[r * 136 + c4 * 4 + 1] = f2h(v.y);
        sh16[r * 136 + c4 * 4 + 2] = f2h(v.z);
        sh16[r * 136 + c4 * 4 + 3] = f2h(v.w);
        float s = v.x * v.x + v.y * v.y + v.z * v.z + v.w * v.w;
        s += __shfl_xor(s, 1);
        s += __shfl_xor(s, 2);
        s += __shfl_xor(s, 4);
        s += __shfl_xor(s, 8);
        s += __shfl_xor(s, 16);
        if ((tid & 31) == 0) h2L[r] = s;
    }
    __syncthreads();

    // ---- phase A: S = h.R^T (fp16 mfma), e = exp(-dist), row sums ----
    half8v afr[4];
#pragma unroll
    for (int ks = 0; ks < 4; ++ks)
        afr[ks] = *(const half8v*)&sh16[c * 136 + ks * 32 + g * 8];
    float h2a[4];
#pragma unroll
    for (int i = 0; i < 4; ++i) h2a[i] = h2L[4 * g + i];

#pragma unroll
    for (int tt = 0; tt < 2; ++tt) {
        const int tile = wv * 2 + tt;        // 16 col-tiles over 8 waves
        const int kc = tile * 16 + c;
        floatx4 acc = {0.f, 0.f, 0.f, 0.f};
#pragma unroll
        for (int ks = 0; ks < 4; ++ks) {
            const half8v b = *(const half8v*)(Rf16 + (size_t)kc * D_LAT + ks * 32 + g * 8);
            acc = __builtin_amdgcn_mfma_f32_16x16x32_f16(afr[ks], b, acc, 0, 0, 0);
        }
        const float r2v = r2w[kc];
#pragma unroll
        for (int i = 0; i < 4; ++i) {
            const float d2 = h2a[i] + r2v - 2.0f * acc[i];
            const float e = __expf(-sqrtf(fmaxf(d2, 0.f)));
            eLp[(4 * g + i) * 264 + kc] = f2bf(e);
            float v = e;                      // sum over the 16 kc of this tile
            v += __shfl_xor(v, 1);
            v += __shfl_xor(v, 2);
            v += __shfl_xor(v, 4);
            v += __shfl_xor(v, 8);
            if (c == 0) sumsL[4 * g + i][tile] = v;
        }
    }
    __syncthreads();
    if (tid < 16) {
        float t = 0.f;
#pragma unroll
        for (int j = 0; j < 16; ++j) t += sumsL[tid][j];
        invL[tid] = 1.0f / (t + EPS_F);
    }
    __syncthreads();

    // ---- phase B: wc = E.R (bf16 mfma), loss partials ----
    const int dcol = wv * 16 + c;            // 8 d-tiles over 8 waves
    float inva[4];
#pragma unroll
    for (int i = 0; i < 4; ++i) inva[i] = invL[4 * g + i];
    floatx4 acc = {0.f, 0.f, 0.f, 0.f};
#pragma unroll
    for (int ks = 0; ks < 8; ++ks) {
        const short8v ae = *(const short8v*)&eLp[c * 264 + ks * 32 + g * 8];
        const short8v b = *(const short8v*)(Rtb + (size_t)dcol * KC + ks * 32 + g * 8);
        acc = __builtin_amdgcn_mfma_f32_16x16x32_bf16(ae, b, acc, 0, 0, 0);
    }
    float lp = 0.f;
#pragma unroll
    for (int i = 0; i < 4; ++i) {
        const float wc = acc[i] * inva[i];
        const float hv = sh32[(4 * g + i) * 132 + dcol];
        const float df = hv - wc;
        lp = fmaf(df, df, lp);
    }
    for (int off = 32; off > 0; off >>= 1) lp += __shfl_down(lp, off);
    if (lane == 0) swL[wv] = lp;
    __syncthreads();
    if (tid == 0) {
        float t = 0.f;
#pragma unroll
        for (int w = 0; w < 8; ++w) t += swL[w];
        pc[cid] = t;
    }
}

// ---------------------------------------------------------------------------
// Final reduction + means.
// ---------------------------------------------------------------------------
__global__ __launch_bounds__(256) void finalize_kernel(const float* __restrict__ pr,
                                                       const float* __restrict__ pc,
                                                       float* __restrict__ out) {
    const int tid = threadIdx.x;
    float a = 0.f, b = 0.f;
    for (int i = tid; i < 1024; i += 256) a += pr[i];
    for (int i = tid; i < 1024; i += 256) b += pc[i];
    float v = a * (1.0f / ((float)N_ROWS * (float)D_INP)) +
              b * (1.0f / ((float)N_ROWS * (float)D_LAT));
    for (int off = 32; off > 0; off >>= 1) v += __shfl_down(v, off);
    __shared__ float sw[4];
    if ((tid & 63) == 0) sw[tid >> 6] = v;
    __syncthreads();
    if (tid == 0) out[0] = sw[0] + sw[1] + sw[2] + sw[3];
}

extern "C" void kernel_launch(void* const* d_in, const int* in_sizes, int n_in,
                              void* d_out, int out_size, void* d_ws, size_t ws_size,
                              hipStream_t stream) {
    const float* x = (const float*)d_in[0];
    const float* h = (const float*)d_in[1];
    const float* a = (const float*)d_in[2];
    const float* R = (const float*)d_in[3];
    float* out = (float*)d_out;
    char* wsb = (char*)d_ws;
    float* pr = (float*)(wsb + 0);                       // 1024 f
    float* pc = (float*)(wsb + 8192);                    // 1024 f
    float* r2 = (float*)(wsb + 12288);                   // 256 f
    unsigned short* Rf16 = (unsigned short*)(wsb + 16384);          // 64 KiB
    unsigned short* Rtb  = (unsigned short*)(wsb + 16384 + 65536);  // 64 KiB

    prep_kernel<<<128, 256, 0, stream>>>(R, Rf16, Rtb, r2);
    fused_kernel<<<2048, 512, 0, stream>>>(x, a, h, Rf16, Rtb, r2, pr, pc);
    finalize_kernel<<<1, 256, 0, stream>>>(pr, pc, out);
}